// Round 8
// baseline (715.421 us; speedup 1.0000x reference)
//
#include <hip/hip_runtime.h>
#include <hip/hip_bf16.h>

// Shapes: B=512, S=128, D=128, HS=256, 4HS=1024, O=1.
// Pipeline (all bf16 MFMA, f32 accum):
//   prepw: WaT/VaT/WT transposed bf16 weights + U_eff packed into MFMA B-fragment order
//          where U_eff = U + fcW^T (x) Wy  (rank-1 fold of the y_prev@Wy recurrence term)
//   prept: H -> per-b LDS-tiled transpose HT[b][d][s] (bf16)
//   k_att:  FUSED per-b: T1 = tanh(H_b@Wa+ba); beta = softmax(T1@Va); pool = beta@H_b.
//   k_gx:   Gx = pool @ W + bias + fc_b*Wy (+ (y0-fc_b)*Wy at t==0),
//           packed [g128][t128][ws8][r16][row4][nt8] bf16 -> 16B stores,
//           4x16B reads by k_seq's q==0 owner lanes.
//   k_seq:  128 blocks x 4 batch rows (the L2-bandwidth sweet spot: U restream
//           traffic 6.3TB = 183us floor vs 365us at 256 blocks). R3 geometry with
//           the three proven fixes ported on: conflict-free stride-36 exchange
//           (16B-aligned f32x4 writes), Gx pre-added into acc before the exchange
//           (no bf16 unpack in the cell), lgkm-only per-step barrier so the delayed
//           h-store and prefetches float across steps.
//           U residency: kc0-2,5,6 nominal-reg (compiler restreams under its 128 cap,
//           ~16TB/s at this block count - hideable), kc3-4 in LDS, kc7 streamed.

using bf16x8 = __attribute__((ext_vector_type(8))) short;
using f32x4  = __attribute__((ext_vector_type(4))) float;
using f32x2  = __attribute__((ext_vector_type(2))) float;

#define DEV static __device__ __forceinline__

DEV unsigned short f2bf(float x) {
    unsigned u = __float_as_uint(x);
    u += 0x7fffu + ((u >> 16) & 1u);          // round-to-nearest-even
    return (unsigned short)(u >> 16);
}
DEV float bf2f(unsigned short s) { return __uint_as_float(((unsigned)s) << 16); }
DEV float sigm(float x) { return 1.0f / (1.0f + __expf(-x)); }
DEV float tanh_f(float x) { float e = __expf(2.0f * x); return 1.0f - 2.0f / (e + 1.0f); }
DEV f32x4 mfma16(bf16x8 a, bf16x8 b, f32x4 c) {
    return __builtin_amdgcn_mfma_f32_16x16x32_bf16(a, b, c, 0, 0, 0);
}

// stage rows x 128 bf16 (row stride 128) into LDS with padded stride 136
DEV void stage128(const unsigned short* __restrict__ src, unsigned short* dst, int rows, int tid) {
    int chunks = rows * 16;
    for (int i = tid; i < chunks; i += 256) {
        int r = i >> 4, c = (i & 15) << 3;
        *(bf16x8*)(dst + r * 136 + c) = *(const bf16x8*)(src + r * 128 + c);
    }
}
// stage rows x 128 f32 -> bf16 LDS (stride 136)
DEV void stage128f(const float* __restrict__ src, unsigned short* dst, int rows, int tid) {
    int chunks = rows * 16;
    for (int i = tid; i < chunks; i += 256) {
        int r = i >> 4, c = (i & 15) << 3;
        const float* s = src + r * 128 + c;
        bf16x8 o;
        #pragma unroll
        for (int e = 0; e < 8; ++e) o[e] = (short)f2bf(s[e]);
        *(bf16x8*)(dst + r * 136 + c) = o;
    }
}

// ---------------- prep kernels ----------------
__global__ void k_prepw(const float* __restrict__ Wa, const float* __restrict__ Va,
                        const float* __restrict__ W, const float* __restrict__ U,
                        const float* __restrict__ fcW, const float* __restrict__ Wy,
                        unsigned short* __restrict__ WaT, unsigned short* __restrict__ VaT,
                        unsigned short* __restrict__ WT, unsigned short* __restrict__ Upk) {
    int idx = blockIdx.x * 256 + threadIdx.x;
    if (idx < 16384) {
        int n = idx >> 7, k = idx & 127;
        WaT[idx] = f2bf(Wa[k * 128 + n]);
    } else if (idx < 32768) {
        int i = idx - 16384;
        int n = i >> 7, k = i & 127;
        VaT[i] = f2bf(Va[k * 128 + n]);
    } else if (idx < 163840) {
        int i = idx - 32768;
        int n = i >> 7, k = i & 127;
        WT[i] = f2bf(W[k * 1024 + n]);
    } else if (idx < 425984) {
        int i = idx - 163840;   // layout: ((((w*8+kc)*8+tt)*64+l)*8+j
        int j = i & 7, ll = (i >> 3) & 63, tt = (i >> 9) & 7, kc = (i >> 12) & 7, w = i >> 15;
        int k = kc * 32 + (ll >> 4) * 8 + j;
        int n = (tt >> 1) * 256 + w * 32 + (tt & 1) * 16 + (ll & 15);
        // rank-1 fold: U_eff = U + fcW^T Wy
        Upk[i] = f2bf(U[k * 1024 + n] + fcW[k] * Wy[n]);
    }
}

// per-b LDS-tiled transpose: HT[b][d][s] (bf16)
__global__ __launch_bounds__(256) void k_prept(const float* __restrict__ H,
                                               unsigned short* __restrict__ HT) {
    __shared__ unsigned short tl[128 * 130];
    int b = blockIdx.x, tid = threadIdx.x;
    const float* Hb = H + (size_t)b * 16384;
    for (int i = tid; i < 16384; i += 256) {
        int s = i >> 7, d = i & 127;
        tl[s * 130 + d] = f2bf(Hb[i]);
    }
    __syncthreads();
    unsigned short* HTb = HT + (size_t)b * 16384;
    for (int i = tid; i < 16384; i += 256) {
        int d = i >> 7, s = i & 127;
        HTb[i] = tl[s * 130 + d];
    }
}

// ---------------- FUSED attention: T1 -> softmax -> pool, one block per b ----------------
__global__ __launch_bounds__(256) void k_att(const float* __restrict__ H,
                                             const unsigned short* __restrict__ WaT,
                                             const unsigned short* __restrict__ VaT,
                                             const unsigned short* __restrict__ HT,
                                             const float* __restrict__ ba,
                                             unsigned short* __restrict__ poolT) {
    __shared__ unsigned short A1[128 * 136];
    __shared__ unsigned short B1[128 * 136];
    int tid = threadIdx.x, b = blockIdx.x;
    int w = tid >> 6, l = tid & 63, q = l >> 4, r = l & 15;

    // phase 1: T1 = tanh(H_b @ WaT + ba)
    stage128f(H + (size_t)b * 16384, A1, 128, tid);
    stage128(WaT, B1, 128, tid);
    __syncthreads();
    f32x4 acc[2][8] = {};
    #pragma unroll
    for (int kc = 0; kc < 4; ++kc)
        #pragma unroll
        for (int mt = 0; mt < 2; ++mt) {
            bf16x8 a = *(const bf16x8*)(A1 + (w * 32 + mt * 16 + r) * 136 + kc * 32 + q * 8);
            #pragma unroll
            for (int nt = 0; nt < 8; ++nt) {
                bf16x8 bb = *(const bf16x8*)(B1 + (nt * 16 + r) * 136 + kc * 32 + q * 8);
                acc[mt][nt] = mfma16(a, bb, acc[mt][nt]);
            }
        }
    __syncthreads();
    // T1 -> B1 (bf16, A-layout); VaT -> A1
    #pragma unroll
    for (int nt = 0; nt < 8; ++nt) {
        float bav = ba[nt * 16 + r];
        #pragma unroll
        for (int mt = 0; mt < 2; ++mt)
            #pragma unroll
            for (int j = 0; j < 4; ++j)
                B1[(w * 32 + mt * 16 + q * 4 + j) * 136 + nt * 16 + r] =
                    f2bf(tanh_f(acc[mt][nt][j] + bav));
    }
    stage128(VaT, A1, 128, tid);
    __syncthreads();

    // phase 2: logits = T1 @ VaT, softmax in-register
    f32x4 lacc[2][8] = {};
    #pragma unroll
    for (int kc = 0; kc < 4; ++kc)
        #pragma unroll
        for (int mt = 0; mt < 2; ++mt) {
            bf16x8 a = *(const bf16x8*)(B1 + (w * 32 + mt * 16 + r) * 136 + kc * 32 + q * 8);
            #pragma unroll
            for (int nt = 0; nt < 8; ++nt) {
                bf16x8 bb = *(const bf16x8*)(A1 + (nt * 16 + r) * 136 + kc * 32 + q * 8);
                lacc[mt][nt] = mfma16(a, bb, lacc[mt][nt]);
            }
        }
    float inv_[2][4];
    #pragma unroll
    for (int mt = 0; mt < 2; ++mt)
        #pragma unroll
        for (int j = 0; j < 4; ++j) {
            float mx = lacc[mt][0][j];
            #pragma unroll
            for (int nt = 1; nt < 8; ++nt) mx = fmaxf(mx, lacc[mt][nt][j]);
            mx = fmaxf(mx, __shfl_xor(mx, 1));
            mx = fmaxf(mx, __shfl_xor(mx, 2));
            mx = fmaxf(mx, __shfl_xor(mx, 4));
            mx = fmaxf(mx, __shfl_xor(mx, 8));
            float s = 0.f;
            #pragma unroll
            for (int nt = 0; nt < 8; ++nt) {
                float e = __expf(lacc[mt][nt][j] - mx);
                lacc[mt][nt][j] = e;
                s += e;
            }
            s += __shfl_xor(s, 1);
            s += __shfl_xor(s, 2);
            s += __shfl_xor(s, 4);
            s += __shfl_xor(s, 8);
            inv_[mt][j] = 1.0f / s;
        }
    __syncthreads();
    // beta -> B1; HT_b -> A1
    #pragma unroll
    for (int mt = 0; mt < 2; ++mt)
        #pragma unroll
        for (int nt = 0; nt < 8; ++nt)
            #pragma unroll
            for (int j = 0; j < 4; ++j)
                B1[(w * 32 + mt * 16 + q * 4 + j) * 136 + nt * 16 + r] =
                    f2bf(lacc[mt][nt][j] * inv_[mt][j]);
    stage128(HT + (size_t)b * 16384, A1, 128, tid);
    __syncthreads();

    // phase 3: pool = beta @ HT_b -> poolT[b][t][d]
    f32x4 pacc[2][8] = {};
    #pragma unroll
    for (int kc = 0; kc < 4; ++kc)
        #pragma unroll
        for (int mt = 0; mt < 2; ++mt) {
            bf16x8 a = *(const bf16x8*)(B1 + (w * 32 + mt * 16 + r) * 136 + kc * 32 + q * 8);
            #pragma unroll
            for (int nt = 0; nt < 8; ++nt) {
                bf16x8 bb = *(const bf16x8*)(A1 + (nt * 16 + r) * 136 + kc * 32 + q * 8);
                pacc[mt][nt] = mfma16(a, bb, pacc[mt][nt]);
            }
        }
    unsigned short* pb = poolT + (size_t)b * 16384;
    #pragma unroll
    for (int mt = 0; mt < 2; ++mt)
        #pragma unroll
        for (int nt = 0; nt < 8; ++nt)
            #pragma unroll
            for (int j = 0; j < 4; ++j)
                pb[(w * 32 + mt * 16 + q * 4 + j) * 128 + nt * 16 + r] = f2bf(pacc[mt][nt][j]);
}

// ---------------- Gx = pool @ W + bias + y-term ----------------
// block = (b, t-half, ws col-group): all 4 gates of a 32-col slice.
// Gxp layout: ((((g*128 + t)*8 + ws)*16 + r)*32 + rw*8 + nt  (shorts)
//   -> 16B stores here; k_seq q==0 lane reads 4x16B (rows 0..3) at r*32.
__global__ __launch_bounds__(256) void k_gx(const unsigned short* __restrict__ poolT,
                                            const unsigned short* __restrict__ WT,
                                            const float* __restrict__ bias,
                                            const float* __restrict__ Wy,
                                            const float* __restrict__ y0,
                                            const float* __restrict__ fcb,
                                            unsigned short* __restrict__ Gxp) {
    __shared__ unsigned short a_lds[64 * 136];
    __shared__ unsigned short b_lds[128 * 136];
    int tid = threadIdx.x;
    int b = blockIdx.x >> 4;
    int thalf = (blockIdx.x >> 3) & 1;
    int ws = blockIdx.x & 7;
    stage128(poolT + (size_t)b * 16384 + thalf * 64 * 128, a_lds, 64, tid);
    #pragma unroll
    for (int gate = 0; gate < 4; ++gate)
        stage128(WT + (size_t)(gate * 256 + ws * 32) * 128, b_lds + gate * 32 * 136, 32, tid);
    __syncthreads();
    int w = tid >> 6, l = tid & 63, q = l >> 4, r = l & 15;
    f32x4 acc[8] = {};
    #pragma unroll
    for (int kc = 0; kc < 4; ++kc) {
        bf16x8 a = *(const bf16x8*)(a_lds + (w * 16 + r) * 136 + kc * 32 + q * 8);
        #pragma unroll
        for (int nt = 0; nt < 8; ++nt) {
            bf16x8 bb = *(const bf16x8*)(b_lds + (nt * 16 + r) * 136 + kc * 32 + q * 8);
            acc[nt] = mfma16(a, bb, acc[nt]);
        }
    }
    int g = b >> 2, rw = b & 3;      // batch group of 4, row within group
    float fcb0 = fcb[0], y00 = y0[b];
    float bv[8], wv[8];
    #pragma unroll
    for (int nt = 0; nt < 8; ++nt) {
        int col = (nt >> 1) * 256 + ws * 32 + (nt & 1) * 16 + r;
        bv[nt] = bias[col];
        wv[nt] = Wy[col];
    }
    #pragma unroll
    for (int j = 0; j < 4; ++j) {
        int t = thalf * 64 + w * 16 + q * 4 + j;
        float yb = (t == 0) ? y00 : fcb0;
        bf16x8 o;
        #pragma unroll
        for (int nt = 0; nt < 8; ++nt)
            o[nt] = (short)f2bf(acc[nt][j] + bv[nt] + yb * wv[nt]);
        size_t addr = ((((size_t)g * 128 + t) * 8 + ws) * 16 + r) * 32 + rw * 8;
        *(bf16x8*)(Gxp + addr) = o;   // 16B store
    }
}

// ---------------- sequential LSTM: 128 blocks x 4 batch rows ----------------
// dynbuf: U kc3-4 (131072) | h 5-row-slot dbuf (5120) | scr stride-36 (18432) | ypart (128)
__global__ __launch_bounds__(512, 2) void k_seq(const unsigned short* __restrict__ Gxp,
                                                const unsigned short* __restrict__ Upk,
                                                const float* __restrict__ fcW,
                                                const float* __restrict__ fcb,
                                                float* __restrict__ out) {
    extern __shared__ __align__(16) char dynbuf[];
    unsigned short* u2   = (unsigned short*)dynbuf;             // 65536 shorts (kc3,4)
    unsigned short* h_fl = (unsigned short*)(dynbuf + 131072);  // 2 x 1280 shorts
    float* scr           = (float*)(dynbuf + 136192);           // [8w][16r][36] f32
    float* ypart         = (float*)(dynbuf + 154624);           // [8w][4row]

    int tid = threadIdx.x;
    int g = blockIdx.x;                 // batch group of 4 rows
    int w = tid >> 6, l = tid & 63, q = l >> 4, r = l & 15;
    int rr = (r < 4) ? r : 4;           // A-frag row; 4 = shared zero row
    float fc_b0 = fcb[0];

    // nominal register-resident U_eff: kc 0,1,2,5,6 (compiler restreams under its cap;
    // at 128 blocks the restream is ~16 TB/s, below the L2 ceiling -> hideable)
    bf16x8 u_res[5][8];
    {
        const bf16x8* up = (const bf16x8*)Upk;
        const int kcs[5] = {0, 1, 2, 5, 6};
        #pragma unroll
        for (int i = 0; i < 5; ++i)
            #pragma unroll
            for (int tt = 0; tt < 8; ++tt)
                u_res[i][tt] = up[((w * 8 + kcs[i]) * 8 + tt) * 64 + l];
    }
    // LDS-resident U_eff: kc 3..4
    #pragma unroll
    for (int kcL = 0; kcL < 2; ++kcL)
        #pragma unroll
        for (int tt = 0; tt < 8; ++tt) {
            size_t gofs = (size_t)(((w * 8 + 3 + kcL) * 8 + tt) * 64 + l) * 8;
            size_t lofs = (size_t)(((w * 2 + kcL) * 8 + tt) * 64 + l) * 8;
            *(bf16x8*)(u2 + lofs) = *(const bf16x8*)(Upk + gofs);
        }

    float fw0 = fcW[w * 32 + ((q & 1) << 4) + r];
    float c_st[2] = {}, hv_st[2] = {};

    for (int i = tid; i < 2560; i += 512) h_fl[i] = 0;   // h(0)=0, zero rows stay zero
    __syncthreads();

    // per-lane pointers
    const unsigned short* gxq = Gxp + (size_t)g * 524288 + w * 512 + r * 32;  // +4096/t, q==0
    const bf16x8* u7p = (const bf16x8*)Upk + (w * 8 + 7) * 512 + l;           // kc7 stream
    float* outp = out + 512 + (size_t)(g * 4 + (q & 2)) * 32768 + w * 32 + ((q & 1) << 4) + r;
    float* scw = scr + (w * 16 + r) * 36;                       // exchange write row
    const float* scrd = scw + ((q & 1) << 2) + (q & 2);         // read base: + gp*8

    for (int t = 0; t < 128; ++t) {
        unsigned short* hp = h_fl + (t & 1) * 1280;
        unsigned short* hn = h_fl + ((t & 1) ^ 1) * 1280;

        // ---- delayed global store of previous step's h (floats across barriers) ----
        if (t > 0) {
            outp[0] = hv_st[0];
            outp[32768] = hv_st[1];
            outp += 256;
        }

        // ---- streamed U kc7: issued at step top, consumed last ----
        bf16x8 u7[8];
        #pragma unroll
        for (int tt = 0; tt < 8; ++tt) u7[tt] = u7p[tt * 64];

        // ---- Gx prefetch: q==0 owner lanes read 4 rows x 8 gate-cols (4x16B) ----
        bf16x8 gxv[4];
        if (q == 0) {
            #pragma unroll
            for (int j2 = 0; j2 < 4; ++j2) gxv[j2] = *(const bf16x8*)(gxq + j2 * 8);
        }

        // ---- MFMA: gates partial = h_prev @ U_eff ----
        f32x4 acc[8] = {};
        #pragma unroll
        for (int i = 0; i < 3; ++i) {          // reg kc 0..2
            bf16x8 a = *(const bf16x8*)(hp + ((i * 4 + q) * 5 + rr) * 8);
            #pragma unroll
            for (int tt = 0; tt < 8; ++tt) acc[tt] = mfma16(a, u_res[i][tt], acc[tt]);
        }
        #pragma unroll
        for (int kcL = 0; kcL < 2; ++kcL) {    // LDS kc 3..4
            bf16x8 a = *(const bf16x8*)(hp + (((3 + kcL) * 4 + q) * 5 + rr) * 8);
            #pragma unroll
            for (int tt = 0; tt < 8; ++tt) {
                bf16x8 u = *(const bf16x8*)(u2 + (size_t)(((w * 2 + kcL) * 8 + tt) * 64 + l) * 8);
                acc[tt] = mfma16(a, u, acc[tt]);
            }
        }
        #pragma unroll
        for (int i = 0; i < 2; ++i) {          // reg kc 5..6
            bf16x8 a = *(const bf16x8*)(hp + (((5 + i) * 4 + q) * 5 + rr) * 8);
            #pragma unroll
            for (int tt = 0; tt < 8; ++tt) acc[tt] = mfma16(a, u_res[3 + i][tt], acc[tt]);
        }
        {                                      // streamed kc7
            bf16x8 a = *(const bf16x8*)(hp + ((7 * 4 + q) * 5 + rr) * 8);
            #pragma unroll
            for (int tt = 0; tt < 8; ++tt) acc[tt] = mfma16(a, u7[tt], acc[tt]);
        }

        // ---- add Gx pre-exchange (q==0 lanes own the 4 valid rows) ----
        if (q == 0) {
            #pragma unroll
            for (int tt = 0; tt < 8; ++tt)
                #pragma unroll
                for (int j = 0; j < 4; ++j)
                    acc[tt][j] += bf2f((unsigned short)gxv[j][tt]);
        }

        // ---- wave-local exchange: conflict-free stride-36 rows, 16B-aligned ----
        if (q == 0) {
            #pragma unroll
            for (int tt = 0; tt < 8; ++tt)
                *(f32x4*)(scw + tt * 4) = acc[tt];
        }
        asm volatile("s_waitcnt lgkmcnt(0)" ::: "memory");
        __builtin_amdgcn_sched_barrier(0);
        float av[4][2];
        #pragma unroll
        for (int gp = 0; gp < 4; ++gp) {
            f32x2 p = *(const f32x2*)(scrd + gp * 8);
            av[gp][0] = p[0];
            av[gp][1] = p[1];
        }

        // ---- LSTM cell: 2 values/lane, rows (q&2)+jj, col w*32+(q&1)*16+r ----
        float ypj[2];
        #pragma unroll
        for (int jj = 0; jj < 2; ++jj) {
            float iv = sigm(av[0][jj]);
            float fv = sigm(av[1][jj]);
            float gv = tanh_f(av[2][jj]);
            float ov = sigm(av[3][jj]);
            float c = fv * c_st[jj] + iv * gv;
            c_st[jj] = c;
            float hv = ov * tanh_f(c);
            int row = (q & 2) + jj;
            // h write in A-fragment order: slot = kc(w)*4 + qd, 5-row slots
            hn[((w * 4 + ((q & 1) << 1) + (r >> 3)) * 5 + row) * 8 + (r & 7)] = f2bf(hv);
            hv_st[jj] = hv;
            ypj[jj] = hv * fw0;
        }
        if (t == 127) {   // final y = fc(h_127) + fc_b, exact f32 path
            #pragma unroll
            for (int jj = 0; jj < 2; ++jj) {
                float v = ypj[jj];
                v += __shfl_xor(v, 1);
                v += __shfl_xor(v, 2);
                v += __shfl_xor(v, 4);
                v += __shfl_xor(v, 8);
                v += __shfl_xor(v, 16);        // combine (q&1) column halves
                if (r == 0 && !(q & 1)) ypart[w * 4 + (q & 2) + jj] = v;
            }
        }
        gxq += 4096;
        // ---- lgkm-only barrier: h LDS visibility without vmcnt drain ----
        asm volatile("s_waitcnt lgkmcnt(0)\n\ts_barrier" ::: "memory");
    }

    // final step's h store
    outp[0] = hv_st[0];
    outp[32768] = hv_st[1];

    __syncthreads();
    if (tid < 4) {
        float y = fc_b0;
        #pragma unroll
        for (int ww = 0; ww < 8; ++ww) y += ypart[ww * 4 + tid];
        out[g * 4 + tid] = y;
    }
}

extern "C" void kernel_launch(void* const* d_in, const int* in_sizes, int n_in,
                              void* d_out, int out_size, void* d_ws, size_t ws_size,
                              hipStream_t stream) {
    const float* H    = (const float*)d_in[0];
    const float* y0   = (const float*)d_in[1];
    const float* Wa   = (const float*)d_in[2];
    // d_in[3] = Ua: multiplied by an all-zero state in the reference -> unused
    const float* ba   = (const float*)d_in[4];
    const float* Va   = (const float*)d_in[5];
    const float* W    = (const float*)d_in[6];
    const float* U    = (const float*)d_in[7];
    const float* bias = (const float*)d_in[8];
    const float* Wy   = (const float*)d_in[9];
    const float* fcW  = (const float*)d_in[10];
    const float* fcb  = (const float*)d_in[11];
    float* out = (float*)d_out;
    char* ws = (char*)d_ws;

    unsigned short* HT    = (unsigned short*)(ws);                      // 16.8 MB
    unsigned short* poolT = (unsigned short*)(ws + 16777216);           // 16.8 MB, [b][t][d]
    unsigned short* Gxp   = (unsigned short*)(ws + 2 * 16777216);       // 134.2 MB
    unsigned short* WaT   = (unsigned short*)(ws + 2 * 16777216 + 134217728);
    unsigned short* VaT   = WaT + 16384;
    unsigned short* WT    = VaT + 16384;
    unsigned short* Upk   = WT + 131072;

    hipFuncSetAttribute((const void*)k_seq, hipFuncAttributeMaxDynamicSharedMemorySize, 154752);

    hipLaunchKernelGGL(k_prepw, dim3(1664), dim3(256), 0, stream, Wa, Va, W, U, fcW, Wy,
                       WaT, VaT, WT, Upk);
    hipLaunchKernelGGL(k_prept, dim3(512), dim3(256), 0, stream, H, HT);
    hipLaunchKernelGGL(k_att, dim3(512), dim3(256), 0, stream, H, WaT, VaT, HT, ba, poolT);
    hipLaunchKernelGGL(k_gx, dim3(8192), dim3(256), 0, stream, poolT, WT, bias, Wy, y0, fcb, Gxp);
    hipLaunchKernelGGL(k_seq, dim3(128), dim3(512), 154752, stream, Gxp, Upk, fcW, fcb, out);
}

// Round 10
// 485.629 us; speedup vs baseline: 1.4732x; 1.4732x over previous
//
#include <hip/hip_runtime.h>
#include <hip/hip_bf16.h>

// Shapes: B=512, S=128, D=128, HS=256, 4HS=1024, O=1.
// Pipeline (all bf16 MFMA, f32 accum):
//   prepw: WaT/VaT/WT transposed bf16 weights + U_eff packed into MFMA B-fragment order
//          where U_eff = U + fcW^T (x) Wy  (rank-1 fold of the y_prev@Wy recurrence term)
//   prept: H -> per-b LDS-tiled transpose HT[b][d][s] (bf16)
//   k_att:  FUSED per-b: T1 = tanh(H_b@Wa+ba); beta = softmax(T1@Va); pool = beta@H_b.
//   k_gx:   Gx = pool @ W + bias + fc_b*Wy (+ (y0-fc_b)*Wy at t==0),
//           packed [g128][t128][ws8][lane64][gate2ch8] bf16 -> 16B stores, and one
//           16B read per k_seq lane.
//   k_seq:  128 blocks x 4 batch rows, EXCHANGE-FREE: batch rows placed at MFMA A
//           rows {0,4,8,12}, so C rows 4q land at reg j=0 of lane group q -- every
//           lane holds its own 2 complete h-values (4 gates x 2 cols) in acc[tt][0].
//           No LDS scratch, no post-MFMA cross-lane traffic at all.
//           U residency: kc0-2,5,6 nominal-reg (compiler restreams under its 128 cap),
//           kc3-4 in LDS, kc7 streamed with step-top issue. lgkm-only per-step barrier;
//           global h stores delayed one step and floating across barriers.

using bf16x8 = __attribute__((ext_vector_type(8))) short;
using f32x4  = __attribute__((ext_vector_type(4))) float;

#define DEV static __device__ __forceinline__

DEV unsigned short f2bf(float x) {
    unsigned u = __float_as_uint(x);
    u += 0x7fffu + ((u >> 16) & 1u);          // round-to-nearest-even
    return (unsigned short)(u >> 16);
}
DEV float bf2f(unsigned short s) { return __uint_as_float(((unsigned)s) << 16); }
DEV float sigm(float x) { return 1.0f / (1.0f + __expf(-x)); }
DEV float tanh_f(float x) { float e = __expf(2.0f * x); return 1.0f - 2.0f / (e + 1.0f); }
DEV f32x4 mfma16(bf16x8 a, bf16x8 b, f32x4 c) {
    return __builtin_amdgcn_mfma_f32_16x16x32_bf16(a, b, c, 0, 0, 0);
}

// stage rows x 128 bf16 (row stride 128) into LDS with padded stride 136
DEV void stage128(const unsigned short* __restrict__ src, unsigned short* dst, int rows, int tid) {
    int chunks = rows * 16;
    for (int i = tid; i < chunks; i += 256) {
        int r = i >> 4, c = (i & 15) << 3;
        *(bf16x8*)(dst + r * 136 + c) = *(const bf16x8*)(src + r * 128 + c);
    }
}
// stage rows x 128 f32 -> bf16 LDS (stride 136)
DEV void stage128f(const float* __restrict__ src, unsigned short* dst, int rows, int tid) {
    int chunks = rows * 16;
    for (int i = tid; i < chunks; i += 256) {
        int r = i >> 4, c = (i & 15) << 3;
        const float* s = src + r * 128 + c;
        bf16x8 o;
        #pragma unroll
        for (int e = 0; e < 8; ++e) o[e] = (short)f2bf(s[e]);
        *(bf16x8*)(dst + r * 136 + c) = o;
    }
}

// ---------------- prep kernels ----------------
__global__ void k_prepw(const float* __restrict__ Wa, const float* __restrict__ Va,
                        const float* __restrict__ W, const float* __restrict__ U,
                        const float* __restrict__ fcW, const float* __restrict__ Wy,
                        unsigned short* __restrict__ WaT, unsigned short* __restrict__ VaT,
                        unsigned short* __restrict__ WT, unsigned short* __restrict__ Upk) {
    int idx = blockIdx.x * 256 + threadIdx.x;
    if (idx < 16384) {
        int n = idx >> 7, k = idx & 127;
        WaT[idx] = f2bf(Wa[k * 128 + n]);
    } else if (idx < 32768) {
        int i = idx - 16384;
        int n = i >> 7, k = i & 127;
        VaT[i] = f2bf(Va[k * 128 + n]);
    } else if (idx < 163840) {
        int i = idx - 32768;
        int n = i >> 7, k = i & 127;
        WT[i] = f2bf(W[k * 1024 + n]);
    } else if (idx < 425984) {
        int i = idx - 163840;   // layout: ((((w*8+kc)*8+tt)*64+l)*8+j
        int j = i & 7, ll = (i >> 3) & 63, tt = (i >> 9) & 7, kc = (i >> 12) & 7, w = i >> 15;
        int k = kc * 32 + (ll >> 4) * 8 + j;
        int n = (tt >> 1) * 256 + w * 32 + (tt & 1) * 16 + (ll & 15);
        // rank-1 fold: U_eff = U + fcW^T Wy
        Upk[i] = f2bf(U[k * 1024 + n] + fcW[k] * Wy[n]);
    }
}

// per-b LDS-tiled transpose: HT[b][d][s] (bf16)
__global__ __launch_bounds__(256) void k_prept(const float* __restrict__ H,
                                               unsigned short* __restrict__ HT) {
    __shared__ unsigned short tl[128 * 130];
    int b = blockIdx.x, tid = threadIdx.x;
    const float* Hb = H + (size_t)b * 16384;
    for (int i = tid; i < 16384; i += 256) {
        int s = i >> 7, d = i & 127;
        tl[s * 130 + d] = f2bf(Hb[i]);
    }
    __syncthreads();
    unsigned short* HTb = HT + (size_t)b * 16384;
    for (int i = tid; i < 16384; i += 256) {
        int d = i >> 7, s = i & 127;
        HTb[i] = tl[s * 130 + d];
    }
}

// ---------------- FUSED attention: T1 -> softmax -> pool, one block per b ----------------
__global__ __launch_bounds__(256) void k_att(const float* __restrict__ H,
                                             const unsigned short* __restrict__ WaT,
                                             const unsigned short* __restrict__ VaT,
                                             const unsigned short* __restrict__ HT,
                                             const float* __restrict__ ba,
                                             unsigned short* __restrict__ poolT) {
    __shared__ unsigned short A1[128 * 136];
    __shared__ unsigned short B1[128 * 136];
    int tid = threadIdx.x, b = blockIdx.x;
    int w = tid >> 6, l = tid & 63, q = l >> 4, r = l & 15;

    // phase 1: T1 = tanh(H_b @ WaT + ba)
    stage128f(H + (size_t)b * 16384, A1, 128, tid);
    stage128(WaT, B1, 128, tid);
    __syncthreads();
    f32x4 acc[2][8] = {};
    #pragma unroll
    for (int kc = 0; kc < 4; ++kc)
        #pragma unroll
        for (int mt = 0; mt < 2; ++mt) {
            bf16x8 a = *(const bf16x8*)(A1 + (w * 32 + mt * 16 + r) * 136 + kc * 32 + q * 8);
            #pragma unroll
            for (int nt = 0; nt < 8; ++nt) {
                bf16x8 bb = *(const bf16x8*)(B1 + (nt * 16 + r) * 136 + kc * 32 + q * 8);
                acc[mt][nt] = mfma16(a, bb, acc[mt][nt]);
            }
        }
    __syncthreads();
    // T1 -> B1 (bf16, A-layout); VaT -> A1
    #pragma unroll
    for (int nt = 0; nt < 8; ++nt) {
        float bav = ba[nt * 16 + r];
        #pragma unroll
        for (int mt = 0; mt < 2; ++mt)
            #pragma unroll
            for (int j = 0; j < 4; ++j)
                B1[(w * 32 + mt * 16 + q * 4 + j) * 136 + nt * 16 + r] =
                    f2bf(tanh_f(acc[mt][nt][j] + bav));
    }
    stage128(VaT, A1, 128, tid);
    __syncthreads();

    // phase 2: logits = T1 @ VaT, softmax in-register
    f32x4 lacc[2][8] = {};
    #pragma unroll
    for (int kc = 0; kc < 4; ++kc)
        #pragma unroll
        for (int mt = 0; mt < 2; ++mt) {
            bf16x8 a = *(const bf16x8*)(B1 + (w * 32 + mt * 16 + r) * 136 + kc * 32 + q * 8);
            #pragma unroll
            for (int nt = 0; nt < 8; ++nt) {
                bf16x8 bb = *(const bf16x8*)(A1 + (nt * 16 + r) * 136 + kc * 32 + q * 8);
                lacc[mt][nt] = mfma16(a, bb, lacc[mt][nt]);
            }
        }
    float inv_[2][4];
    #pragma unroll
    for (int mt = 0; mt < 2; ++mt)
        #pragma unroll
        for (int j = 0; j < 4; ++j) {
            float mx = lacc[mt][0][j];
            #pragma unroll
            for (int nt = 1; nt < 8; ++nt) mx = fmaxf(mx, lacc[mt][nt][j]);
            mx = fmaxf(mx, __shfl_xor(mx, 1));
            mx = fmaxf(mx, __shfl_xor(mx, 2));
            mx = fmaxf(mx, __shfl_xor(mx, 4));
            mx = fmaxf(mx, __shfl_xor(mx, 8));
            float s = 0.f;
            #pragma unroll
            for (int nt = 0; nt < 8; ++nt) {
                float e = __expf(lacc[mt][nt][j] - mx);
                lacc[mt][nt][j] = e;
                s += e;
            }
            s += __shfl_xor(s, 1);
            s += __shfl_xor(s, 2);
            s += __shfl_xor(s, 4);
            s += __shfl_xor(s, 8);
            inv_[mt][j] = 1.0f / s;
        }
    __syncthreads();
    // beta -> B1; HT_b -> A1
    #pragma unroll
    for (int mt = 0; mt < 2; ++mt)
        #pragma unroll
        for (int nt = 0; nt < 8; ++nt)
            #pragma unroll
            for (int j = 0; j < 4; ++j)
                B1[(w * 32 + mt * 16 + q * 4 + j) * 136 + nt * 16 + r] =
                    f2bf(lacc[mt][nt][j] * inv_[mt][j]);
    stage128(HT + (size_t)b * 16384, A1, 128, tid);
    __syncthreads();

    // phase 3: pool = beta @ HT_b -> poolT[b][t][d]
    f32x4 pacc[2][8] = {};
    #pragma unroll
    for (int kc = 0; kc < 4; ++kc)
        #pragma unroll
        for (int mt = 0; mt < 2; ++mt) {
            bf16x8 a = *(const bf16x8*)(B1 + (w * 32 + mt * 16 + r) * 136 + kc * 32 + q * 8);
            #pragma unroll
            for (int nt = 0; nt < 8; ++nt) {
                bf16x8 bb = *(const bf16x8*)(A1 + (nt * 16 + r) * 136 + kc * 32 + q * 8);
                pacc[mt][nt] = mfma16(a, bb, pacc[mt][nt]);
            }
        }
    unsigned short* pb = poolT + (size_t)b * 16384;
    #pragma unroll
    for (int mt = 0; mt < 2; ++mt)
        #pragma unroll
        for (int nt = 0; nt < 8; ++nt)
            #pragma unroll
            for (int j = 0; j < 4; ++j)
                pb[(w * 32 + mt * 16 + q * 4 + j) * 128 + nt * 16 + r] = f2bf(pacc[mt][nt][j]);
}

// ---------------- Gx = pool @ W + bias + y-term ----------------
// block = (b, t-half, ws col-group): all 4 gates of a 32-col slice.
// Gxp layout (shorts): (((g*128 + t)*8 + ws)*64 + q_s*16 + r)*8 + gate*2 + ch
//   -> per-lane 16B store here; k_seq lane (q_s,r) of wave ws reads its 16B directly.
__global__ __launch_bounds__(256) void k_gx(const unsigned short* __restrict__ poolT,
                                            const unsigned short* __restrict__ WT,
                                            const float* __restrict__ bias,
                                            const float* __restrict__ Wy,
                                            const float* __restrict__ y0,
                                            const float* __restrict__ fcb,
                                            unsigned short* __restrict__ Gxp) {
    __shared__ unsigned short a_lds[64 * 136];
    __shared__ unsigned short b_lds[128 * 136];
    int tid = threadIdx.x;
    int b = blockIdx.x >> 4;
    int thalf = (blockIdx.x >> 3) & 1;
    int ws = blockIdx.x & 7;
    stage128(poolT + (size_t)b * 16384 + thalf * 64 * 128, a_lds, 64, tid);
    #pragma unroll
    for (int gate = 0; gate < 4; ++gate)
        stage128(WT + (size_t)(gate * 256 + ws * 32) * 128, b_lds + gate * 32 * 136, 32, tid);
    __syncthreads();
    int w = tid >> 6, l = tid & 63, q = l >> 4, r = l & 15;
    f32x4 acc[8] = {};
    #pragma unroll
    for (int kc = 0; kc < 4; ++kc) {
        bf16x8 a = *(const bf16x8*)(a_lds + (w * 16 + r) * 136 + kc * 32 + q * 8);
        #pragma unroll
        for (int nt = 0; nt < 8; ++nt) {
            bf16x8 bb = *(const bf16x8*)(b_lds + (nt * 16 + r) * 136 + kc * 32 + q * 8);
            acc[nt] = mfma16(a, bb, acc[nt]);
        }
    }
    int g = b >> 2, q_s = b & 3;     // batch group of 4, row within group
    float fcb0 = fcb[0], y00 = y0[b];
    float bv[8], wv[8];
    #pragma unroll
    for (int nt = 0; nt < 8; ++nt) {
        int col = (nt >> 1) * 256 + ws * 32 + (nt & 1) * 16 + r;
        bv[nt] = bias[col];
        wv[nt] = Wy[col];
    }
    #pragma unroll
    for (int j = 0; j < 4; ++j) {
        int t = thalf * 64 + w * 16 + q * 4 + j;
        float yb = (t == 0) ? y00 : fcb0;
        bf16x8 o;   // short position nt == gate*2+ch (identity)
        #pragma unroll
        for (int nt = 0; nt < 8; ++nt)
            o[nt] = (short)f2bf(acc[nt][j] + bv[nt] + yb * wv[nt]);
        size_t addr = ((((size_t)g * 128 + t) * 8 + ws) * 64 + q_s * 16 + r) * 8;
        *(bf16x8*)(Gxp + addr) = o;   // 16B store
    }
}

// ---------------- sequential LSTM: 128 blocks x 4 batch rows, EXCHANGE-FREE ----------------
// Batch rows at MFMA A rows {0,4,8,12} -> lane (q,r) holds batch row q at acc[tt][0]:
// gate=tt>>1, col = w*32 + (tt&1)*16 + r. Cell math entirely lane-local.
// dynbuf: U kc3-4 (131072) | h 5-row-slot dbuf (2x1280 shorts = 5120 B) | ypart (128)
__global__ __launch_bounds__(512, 2) void k_seq(const unsigned short* __restrict__ Gxp,
                                                const unsigned short* __restrict__ Upk,
                                                const float* __restrict__ fcW,
                                                const float* __restrict__ fcb,
                                                float* __restrict__ out) {
    extern __shared__ __align__(16) char dynbuf[];
    unsigned short* u2   = (unsigned short*)dynbuf;             // 65536 shorts (kc3,4)
    unsigned short* h_fl = (unsigned short*)(dynbuf + 131072);  // 2 x 1280 shorts
    float* ypart         = (float*)(dynbuf + 136192);           // [8w][4row]

    int tid = threadIdx.x;
    int g = blockIdx.x;                 // batch group of 4 rows
    int w = tid >> 6, l = tid & 63, q = l >> 4, r = l & 15;
    // A-frag row slot: valid rows 0,4,8,12 live in slot-rows 0..3; others read zero row 4
    int rowslot = ((r & 3) == 0) ? (r >> 2) : 4;
    float fc_b0 = fcb[0];

    // nominal register-resident U_eff: kc 0,1,2,5,6 (compiler restreams under its cap)
    bf16x8 u_res[5][8];
    {
        const bf16x8* up = (const bf16x8*)Upk;
        const int kcs[5] = {0, 1, 2, 5, 6};
        #pragma unroll
        for (int i = 0; i < 5; ++i)
            #pragma unroll
            for (int tt = 0; tt < 8; ++tt)
                u_res[i][tt] = up[((w * 8 + kcs[i]) * 8 + tt) * 64 + l];
    }
    // LDS-resident U_eff: kc 3..4
    #pragma unroll
    for (int kcL = 0; kcL < 2; ++kcL)
        #pragma unroll
        for (int tt = 0; tt < 8; ++tt) {
            size_t gofs = (size_t)(((w * 8 + 3 + kcL) * 8 + tt) * 64 + l) * 8;
            size_t lofs = (size_t)(((w * 2 + kcL) * 8 + tt) * 64 + l) * 8;
            *(bf16x8*)(u2 + lofs) = *(const bf16x8*)(Upk + gofs);
        }

    float fw0 = fcW[w * 32 + r];
    float fw1 = fcW[w * 32 + 16 + r];
    float c_st[2] = {}, hv_st[2] = {};

    for (int i = tid; i < 2560; i += 512) h_fl[i] = 0;   // h(0)=0, zero rows stay zero
    __syncthreads();

    // per-lane pointers
    const unsigned short* gxq = Gxp + (((size_t)g * 128 * 8 + w) * 64 + l) * 8;  // +4096/t
    const bf16x8* u7p = (const bf16x8*)Upk + (w * 8 + 7) * 512 + l;              // kc7 stream
    float* outp = out + 512 + (size_t)(g * 4 + q) * 32768 + w * 32 + r;

    for (int t = 0; t < 128; ++t) {
        unsigned short* hp = h_fl + (t & 1) * 1280;
        unsigned short* hn = h_fl + ((t & 1) ^ 1) * 1280;

        // ---- delayed global store of previous step's h (floats across barriers) ----
        if (t > 0) {
            outp[0] = hv_st[0];
            outp[16] = hv_st[1];
            outp += 256;
        }

        // ---- streamed U kc7: issued at step top, consumed last ----
        bf16x8 u7[8];
        #pragma unroll
        for (int tt = 0; tt < 8; ++tt) u7[tt] = u7p[tt * 64];

        // ---- Gx prefetch: one 16B read per lane (its own 8 gate values) ----
        bf16x8 gxv = *(const bf16x8*)gxq;

        // ---- MFMA: gates partial = h_prev @ U_eff ----
        f32x4 acc[8] = {};
        #pragma unroll
        for (int i = 0; i < 3; ++i) {          // reg kc 0..2
            bf16x8 a = *(const bf16x8*)(hp + ((i * 4 + q) * 5 + rowslot) * 8);
            #pragma unroll
            for (int tt = 0; tt < 8; ++tt) acc[tt] = mfma16(a, u_res[i][tt], acc[tt]);
        }
        #pragma unroll
        for (int kcL = 0; kcL < 2; ++kcL) {    // LDS kc 3..4
            bf16x8 a = *(const bf16x8*)(hp + (((3 + kcL) * 4 + q) * 5 + rowslot) * 8);
            #pragma unroll
            for (int tt = 0; tt < 8; ++tt) {
                bf16x8 u = *(const bf16x8*)(u2 + (size_t)(((w * 2 + kcL) * 8 + tt) * 64 + l) * 8);
                acc[tt] = mfma16(a, u, acc[tt]);
            }
        }
        #pragma unroll
        for (int i = 0; i < 2; ++i) {          // reg kc 5..6
            bf16x8 a = *(const bf16x8*)(hp + (((5 + i) * 4 + q) * 5 + rowslot) * 8);
            #pragma unroll
            for (int tt = 0; tt < 8; ++tt) acc[tt] = mfma16(a, u_res[3 + i][tt], acc[tt]);
        }
        {                                      // streamed kc7
            bf16x8 a = *(const bf16x8*)(hp + ((7 * 4 + q) * 5 + rowslot) * 8);
            #pragma unroll
            for (int tt = 0; tt < 8; ++tt) acc[tt] = mfma16(a, u7[tt], acc[tt]);
        }

        // ---- LSTM cell: 2 lane-local values (batch row q, cols w*32+ch*16+r) ----
        float ypj = 0.f;
        #pragma unroll
        for (int ch = 0; ch < 2; ++ch) {
            float iv = sigm(acc[0 + ch][0] + bf2f((unsigned short)gxv[0 + ch]));
            float fv = sigm(acc[2 + ch][0] + bf2f((unsigned short)gxv[2 + ch]));
            float gv = tanh_f(acc[4 + ch][0] + bf2f((unsigned short)gxv[4 + ch]));
            float ov = sigm(acc[6 + ch][0] + bf2f((unsigned short)gxv[6 + ch]));
            float c = fv * c_st[ch] + iv * gv;
            c_st[ch] = c;
            float hv = ov * tanh_f(c);
            // h write: A row 4q -> slot-row q; k-slot = kc(w), qq = ch*2+(r>>3), e = r&7
            hn[((w * 4 + ch * 2 + (r >> 3)) * 5 + q) * 8 + (r & 7)] = f2bf(hv);
            hv_st[ch] = hv;
            ypj += hv * (ch ? fw1 : fw0);
        }
        if (t == 127) {   // final y = fc(h_127) + fc_b, exact f32 path
            float v = ypj;
            v += __shfl_xor(v, 1);
            v += __shfl_xor(v, 2);
            v += __shfl_xor(v, 4);
            v += __shfl_xor(v, 8);
            if (r == 0) ypart[w * 4 + q] = v;
        }
        gxq += 4096;
        // ---- lgkm-only barrier: h LDS visibility without vmcnt drain ----
        asm volatile("s_waitcnt lgkmcnt(0)\n\ts_barrier" ::: "memory");
    }

    // final step's h store
    outp[0] = hv_st[0];
    outp[16] = hv_st[1];

    __syncthreads();
    if (tid < 4) {
        float y = fc_b0;
        #pragma unroll
        for (int ww = 0; ww < 8; ++ww) y += ypart[ww * 4 + tid];
        out[g * 4 + tid] = y;
    }
}

extern "C" void kernel_launch(void* const* d_in, const int* in_sizes, int n_in,
                              void* d_out, int out_size, void* d_ws, size_t ws_size,
                              hipStream_t stream) {
    const float* H    = (const float*)d_in[0];
    const float* y0   = (const float*)d_in[1];
    const float* Wa   = (const float*)d_in[2];
    // d_in[3] = Ua: multiplied by an all-zero state in the reference -> unused
    const float* ba   = (const float*)d_in[4];
    const float* Va   = (const float*)d_in[5];
    const float* W    = (const float*)d_in[6];
    const float* U    = (const float*)d_in[7];
    const float* bias = (const float*)d_in[8];
    const float* Wy   = (const float*)d_in[9];
    const float* fcW  = (const float*)d_in[10];
    const float* fcb  = (const float*)d_in[11];
    float* out = (float*)d_out;
    char* ws = (char*)d_ws;

    unsigned short* HT    = (unsigned short*)(ws);                      // 16.8 MB
    unsigned short* poolT = (unsigned short*)(ws + 16777216);           // 16.8 MB, [b][t][d]
    unsigned short* Gxp   = (unsigned short*)(ws + 2 * 16777216);       // 134.2 MB
    unsigned short* WaT   = (unsigned short*)(ws + 2 * 16777216 + 134217728);
    unsigned short* VaT   = WaT + 16384;
    unsigned short* WT    = VaT + 16384;
    unsigned short* Upk   = WT + 131072;

    hipFuncSetAttribute((const void*)k_seq, hipFuncAttributeMaxDynamicSharedMemorySize, 136320);

    hipLaunchKernelGGL(k_prepw, dim3(1664), dim3(256), 0, stream, Wa, Va, W, U, fcW, Wy,
                       WaT, VaT, WT, Upk);
    hipLaunchKernelGGL(k_prept, dim3(512), dim3(256), 0, stream, H, HT);
    hipLaunchKernelGGL(k_att, dim3(512), dim3(256), 0, stream, H, WaT, VaT, HT, ba, poolT);
    hipLaunchKernelGGL(k_gx, dim3(8192), dim3(256), 0, stream, poolT, WT, bias, Wy, y0, fcb, Gxp);
    hipLaunchKernelGGL(k_seq, dim3(128), dim3(512), 136320, stream, Gxp, Upk, fcW, fcb, out);
}